// Round 10
// baseline (518.150 us; speedup 1.0000x reference)
//
#include <hip/hip_runtime.h>

#define F        4096
#define NE       ((size_t)F * F)

typedef __attribute__((ext_vector_type(8)))  short bf16x8;
typedef __attribute__((ext_vector_type(4)))  float f32x4;

typedef const void __attribute__((address_space(1)))* gas1p;
typedef void __attribute__((address_space(3)))*       as3p;

__device__ __forceinline__ void gload16(const void* g, void* l) {
    __builtin_amdgcn_global_load_lds((gas1p)g, (as3p)l, 16, 0, 0);
}

__device__ __forceinline__ unsigned short f2bf(float f) {
    union { float f; unsigned int u; } c; c.f = f;
    unsigned int u = c.u;
    u += 0x7fffu + ((u >> 16) & 1u);   // RNE
    return (unsigned short)(u >> 16);
}
__device__ __forceinline__ float bf2f(unsigned short u) {
    union { unsigned int u; float f; } c; c.u = ((unsigned int)u) << 16;
    return c.f;
}

__global__ void cvt_all(const float* __restrict__ s0, const float* __restrict__ s1,
                        const float* __restrict__ s2, const float* __restrict__ s3,
                        unsigned short* __restrict__ d0, unsigned short* __restrict__ d1,
                        unsigned short* __restrict__ d2, unsigned short* __restrict__ d3,
                        int n4) {
    const float* src = (blockIdx.y == 0) ? s0 : (blockIdx.y == 1) ? s1
                      : (blockIdx.y == 2) ? s2 : s3;
    unsigned short* dst = (blockIdx.y == 0) ? d0 : (blockIdx.y == 1) ? d1
                         : (blockIdx.y == 2) ? d2 : d3;
    int idx    = blockIdx.x * blockDim.x + threadIdx.x;
    int stride = gridDim.x * blockDim.x;
    const float4* in4 = (const float4*)src;
    ushort4* out4 = (ushort4*)dst;
    for (int i = idx; i < n4; i += stride) {
        float4 v = in4[i];
        ushort4 o;
        o.x = f2bf(v.x); o.y = f2bf(v.y); o.z = f2bf(v.z); o.w = f2bf(v.w);
        out4[i] = o;
    }
}

__device__ __forceinline__ int qo_map(int o) {
    int nblk = o >> 2, g = o & 3;
    return (nblk >> 5) * 128 + (g >> 1) * 64 + (nblk & 31) * 2 + (g & 1);
}

#define MFMA16(a, b, c) __builtin_amdgcn_mfma_f32_16x16x32_bf16(a, b, c, 0, 0, 0)

// ============================================================================
// GEMM: 128x256 tile, 256 threads (4 waves), wave tile 64x128 (same per-FLOP
// LDS traffic as the r3 256² kernel), 3-slot LDS ring = 72 KB -> 2 blocks/CU.
// Two independent barrier groups per CU: one block's MFMA burst overlaps the
// other's ds_read/lgkm burst (m114 separate pipes). All LDS reads JIT from
// slot t%3 (no refill-ahead -> no cross-wave race); stage tile t+2 at iter
// end; vmcnt(6) BEFORE the barrier (r3-proven invariant: after the barrier,
// tile t+1 is visible to all waves). N=12288 (Q|K|V in out-col space).
// ============================================================================
#define GBM 128
#define GBN 256
#define GBK 32
#define NKT (F / GBK)          // 128
#define AELPS (GBM * GBK)      // 4096 elements per A slot
#define BELPS (GBN * GBK)      // 8192 elements per B slot

__launch_bounds__(256, 2)
__global__ void gemm_qkv(const unsigned short* __restrict__ Xb,
                         const unsigned short* __restrict__ Qw,
                         const unsigned short* __restrict__ Kw,
                         const unsigned short* __restrict__ Vw,
                         unsigned short* __restrict__ qkv) {
    __shared__ __align__(16) unsigned short Als[3][GBM][GBK];   // 24 KB
    __shared__ __align__(16) unsigned short Bls[3][GBN][GBK];   // 48 KB

    const int tid  = threadIdx.x;
    const int lane = tid & 63;
    const int wid  = tid >> 6;          // 0..3
    const int wwm  = wid >> 1;          // 0..1 : rows [wwm*64, +64)
    const int wwn  = wid & 1;           // 0..1 : cols [wwn*128, +128)

    // XCD-aware bijective swizzle (1536 % 8 == 0)
    const int bid = blockIdx.x;
    const int swz = (bid & 7) * 192 + (bid >> 3);
    const int mt  = swz & 31;           // 32 M-tiles
    const int nt  = swz >> 5;           // 48 N-tiles
    const int bm  = mt * GBM;
    const int bnG = nt * GBN;
    const int mat = bnG >> 12;
    const int bn  = bnG & 4095;
    const unsigned short* __restrict__ Wsel = (mat == 0) ? Qw : (mat == 1) ? Kw : Vw;

    // ---- staging: 6 gloads/thread/K-tile. Per wave-round: 16 rows.
    // row_local = tid>>2 (0..63); stored slot = tid&3;
    // source chunk = (tid&3)^((row>>1)&3) = (tid&3)^((tid>>3)&3)  [r3-verified]
    const int rloc = tid >> 2;
    const int chn  = (tid & 3) ^ ((tid >> 3) & 3);
    const unsigned short* aSrc0 = Xb + (size_t)(bm + rloc) * F + chn * 8;
    const unsigned short* aSrc1 = aSrc0 + (size_t)64 * F;
    const unsigned short* bSrcR[4];
#pragma unroll
    for (int q = 0; q < 4; ++q)
        bSrcR[q] = Wsel + (size_t)qo_map(bn + q * 64 + rloc) * F + chn * 8;

#define STAGE(s, tt) do {                                                         \
        gload16(aSrc0    + (size_t)(tt) * GBK, (void*)&Als[s][wid * 16][0]);      \
        gload16(aSrc1    + (size_t)(tt) * GBK, (void*)&Als[s][64 + wid * 16][0]); \
        gload16(bSrcR[0] + (size_t)(tt) * GBK, (void*)&Bls[s][wid * 16][0]);      \
        gload16(bSrcR[1] + (size_t)(tt) * GBK, (void*)&Bls[s][64 + wid * 16][0]); \
        gload16(bSrcR[2] + (size_t)(tt) * GBK, (void*)&Bls[s][128 + wid * 16][0]);\
        gload16(bSrcR[3] + (size_t)(tt) * GBK, (void*)&Bls[s][192 + wid * 16][0]);\
    } while (0)

    // ---- fragment read addressing (r3 0-conflict pattern) ----
    const int fr  = lane & 15;
    const int fq  = lane >> 4;
    const int fq2 = fq ^ ((fr >> 1) & 3);
    const unsigned short* aRd = &Als[0][wwm * 64 + fr][fq2 * 8];    // + s*AELPS + mi*512
    const unsigned short* bRd = &Bls[0][wwn * 128 + fr][fq2 * 8];   // + s*BELPS + nj*512

    f32x4 acc[4][8];
#pragma unroll
    for (int mi = 0; mi < 4; ++mi)
#pragma unroll
        for (int nj = 0; nj < 8; ++nj)
            acc[mi][nj] = (f32x4){0.f, 0.f, 0.f, 0.f};

    // ---- prologue: stage tiles 0,1 into slots 0,1 (12 gloads) ----
    STAGE(0, 0);
    STAGE(1, 1);
    asm volatile("s_waitcnt vmcnt(6)" ::: "memory");   // tile 0 resident
    __builtin_amdgcn_s_barrier();

#define MQ(nj, BF) do {                                                           \
        _Pragma("unroll")                                                         \
        for (int mi = 0; mi < 4; ++mi)                                            \
            acc[mi][nj] = MFMA16(af[mi], BF, acc[mi][nj]);                        \
    } while (0)

#define ITER(t, cur, stg, STG) do {                                               \
        const unsigned short* aC = aRd + (cur) * AELPS;                           \
        const unsigned short* bC = bRd + (cur) * BELPS;                           \
        bf16x8 af[4];                                                             \
        _Pragma("unroll")                                                         \
        for (int mi = 0; mi < 4; ++mi)                                            \
            af[mi] = *(const bf16x8*)(aC + mi * 512);                             \
        bf16x8 b0 = *(const bf16x8*)(bC + 0 * 512);                               \
        bf16x8 b1 = *(const bf16x8*)(bC + 1 * 512);                               \
        __builtin_amdgcn_s_setprio(1);                                            \
        MQ(0, b0);  b0 = *(const bf16x8*)(bC + 2 * 512);                          \
        MQ(1, b1);  b1 = *(const bf16x8*)(bC + 3 * 512);                          \
        MQ(2, b0);  b0 = *(const bf16x8*)(bC + 4 * 512);                          \
        MQ(3, b1);  b1 = *(const bf16x8*)(bC + 5 * 512);                          \
        MQ(4, b0);  b0 = *(const bf16x8*)(bC + 6 * 512);                          \
        MQ(5, b1);  b1 = *(const bf16x8*)(bC + 7 * 512);                          \
        MQ(6, b0);                                                                \
        MQ(7, b1);                                                                \
        __builtin_amdgcn_s_setprio(0);                                            \
        if (STG) {                                                                \
            STAGE(stg, (t) + 2);                                                  \
            __builtin_amdgcn_sched_barrier(0);                                    \
            asm volatile("s_waitcnt vmcnt(6)" ::: "memory");                      \
        } else {                                                                  \
            __builtin_amdgcn_sched_barrier(0);                                    \
            asm volatile("s_waitcnt vmcnt(0)" ::: "memory");                      \
        }                                                                         \
        __builtin_amdgcn_sched_barrier(0);                                        \
        __builtin_amdgcn_s_barrier();                                             \
    } while (0)

    for (int t = 0; t < 126; t += 3) {
        ITER(t,     0, 2, true);
        ITER(t + 1, 1, 0, true);
        ITER(t + 2, 2, 1, true);
    }
    ITER(126, 0, 2, false);            // drains tile 127 (vmcnt(0)) then barrier
    {   // tile 127: compute only, slot 1
        const unsigned short* aC = aRd + 1 * AELPS;
        const unsigned short* bC = bRd + 1 * BELPS;
        bf16x8 af[4];
#pragma unroll
        for (int mi = 0; mi < 4; ++mi)
            af[mi] = *(const bf16x8*)(aC + mi * 512);
        bf16x8 b0 = *(const bf16x8*)(bC + 0 * 512);
        bf16x8 b1 = *(const bf16x8*)(bC + 1 * 512);
        MQ(0, b0);  b0 = *(const bf16x8*)(bC + 2 * 512);
        MQ(1, b1);  b1 = *(const bf16x8*)(bC + 3 * 512);
        MQ(2, b0);  b0 = *(const bf16x8*)(bC + 4 * 512);
        MQ(3, b1);  b1 = *(const bf16x8*)(bC + 5 * 512);
        MQ(4, b0);  b0 = *(const bf16x8*)(bC + 6 * 512);
        MQ(5, b1);  b1 = *(const bf16x8*)(bC + 7 * 512);
        MQ(6, b0);
        MQ(7, b1);
    }

    // ---- epilogue: bf16 store in out-col space ----
    // C/D 16x16: col = lane&15 (fr), row = fq*4 + reg
    unsigned short* outB = qkv + (size_t)mat * NE;
#pragma unroll
    for (int mi = 0; mi < 4; ++mi) {
#pragma unroll
        for (int nj = 0; nj < 8; ++nj) {
#pragma unroll
            for (int r = 0; r < 4; ++r) {
                int row = bm + wwm * 64 + mi * 16 + fq * 4 + r;
                int col = bn + wwn * 128 + nj * 16 + fr;
                outB[(size_t)row * F + col] = f2bf(acc[mi][nj][r]);
            }
        }
    }
#undef ITER
#undef MQ
#undef STAGE
}

// ============================================================================
// Attention epilogue: per 4-col block, 4-wide softmax-attention. Memory-bound.
// ============================================================================
__global__ void attn_ep(const unsigned short* __restrict__ qkv,
                        float* __restrict__ out) {
    const size_t NB = NE / 4;
    const ushort4* q4 = (const ushort4*)qkv;
    const ushort4* k4 = q4 + NB;
    const ushort4* v4 = k4 + NB;
    float4* o4 = (float4*)out;
    size_t i      = (size_t)blockIdx.x * blockDim.x + threadIdx.x;
    size_t stride = (size_t)gridDim.x * blockDim.x;
    for (; i < NB; i += stride) {
        ushort4 qu = q4[i], ku = k4[i], vu = v4[i];
        float q0 = bf2f(qu.x), q1 = bf2f(qu.y), q2 = bf2f(qu.z), q3 = bf2f(qu.w);
        float k0 = bf2f(ku.x), k1 = bf2f(ku.y), k2 = bf2f(ku.z), k3 = bf2f(ku.w);
        float v0 = bf2f(vu.x), v1 = bf2f(vu.y), v2 = bf2f(vu.z), v3 = bf2f(vu.w);
        float4 res;
#pragma unroll
        for (int g = 0; g < 4; ++g) {
            float qg = (g == 0) ? q0 : (g == 1) ? q1 : (g == 2) ? q2 : q3;
            float s0 = qg * k0, s1 = qg * k1, s2 = qg * k2, s3 = qg * k3;
            float mx = fmaxf(fmaxf(s0, s1), fmaxf(s2, s3));
            float e0 = __expf(s0 - mx), e1 = __expf(s1 - mx);
            float e2 = __expf(s2 - mx), e3 = __expf(s3 - mx);
            float num = e0 * v0 + e1 * v1 + e2 * v2 + e3 * v3;
            float den = e0 + e1 + e2 + e3;
            float r = num / den;
            if (g == 0) res.x = r; else if (g == 1) res.y = r;
            else if (g == 2) res.z = r; else res.w = r;
        }
        o4[i] = res;
    }
}

// ============================================================================
// Fallback (round-1 fused kernel, verified): used when ws too small for split.
// ============================================================================
#define BM       128
#define BN       128
#define BK       32
#define NTHREADS 512
#define KTILES   (F / BK)

__launch_bounds__(NTHREADS, 1)
__global__ void fused_qkv_attn(const unsigned short* __restrict__ Xb,
                               const unsigned short* __restrict__ Qw,
                               const unsigned short* __restrict__ Kw,
                               const unsigned short* __restrict__ Vw,
                               float* __restrict__ out) {
    __shared__ __align__(16) unsigned short Alds[BM][BK];
    __shared__ __align__(16) unsigned short Blds[3][BN][BK];

    const int tid  = threadIdx.x;
    const int lane = tid & 63;
    const int wid  = tid >> 6;
    const int wm   = wid >> 1;
    const int wn   = wid & 1;

    const int bm = blockIdx.y * BM;
    const int bn = blockIdx.x * BN;

    const int srow   = wid * 16 + (lane >> 2);
    const int kchunk = (lane & 3) ^ ((lane >> 3) & 3);
    const int scol   = kchunk * 8;

    const unsigned short* aG = Xb + (size_t)(bm + srow) * F + scol;
    const int o  = bn + srow;
    const int qo = qo_map(o);
    const unsigned short* qG = Qw + (size_t)qo * F + scol;
    const unsigned short* kG = Kw + (size_t)qo * F + scol;
    const unsigned short* vG = Vw + (size_t)qo * F + scol;

    unsigned short* aL = &Alds[wid * 16][0];
    unsigned short* qL = &Blds[0][wid * 16][0];
    unsigned short* kL = &Blds[1][wid * 16][0];
    unsigned short* vL = &Blds[2][wid * 16][0];

    const int fr  = lane & 15;
    const int fq  = lane >> 4;
    const int fq2 = fq ^ ((fr >> 1) & 3);

    const unsigned short* aP[2];
#pragma unroll
    for (int m = 0; m < 2; ++m)
        aP[m] = &Alds[wm * 32 + m * 16 + fr][fq2 * 8];
    const unsigned short* bP[4];
#pragma unroll
    for (int n = 0; n < 4; ++n)
        bP[n] = &Blds[0][wn * 64 + n * 16 + fr][fq2 * 8];

    f32x4 acc[3][2][4];
#pragma unroll
    for (int t = 0; t < 3; ++t)
#pragma unroll
        for (int m = 0; m < 2; ++m)
#pragma unroll
            for (int n = 0; n < 4; ++n)
                acc[t][m][n] = (f32x4){0.f, 0.f, 0.f, 0.f};

    for (int kt = 0; kt < KTILES; ++kt) {
        gload16(aG, aL);
        gload16(qG, qL);
        gload16(kG, kL);
        gload16(vG, vL);
        aG += BK; qG += BK; kG += BK; vG += BK;
        __syncthreads();

        bf16x8 afr[2];
#pragma unroll
        for (int m = 0; m < 2; ++m)
            afr[m] = *(const bf16x8*)aP[m];

#pragma unroll
        for (int t = 0; t < 3; ++t) {
#pragma unroll
            for (int n = 0; n < 4; ++n) {
                bf16x8 bfr = *(const bf16x8*)(bP[n] + t * (BN * BK));
#pragma unroll
                for (int m = 0; m < 2; ++m)
                    acc[t][m][n] = MFMA16(afr[m], bfr, acc[t][m][n]);
            }
        }
        __syncthreads();
    }

#pragma unroll
    for (int m = 0; m < 2; ++m) {
#pragma unroll
        for (int n = 0; n < 4; ++n) {
#pragma unroll
            for (int r = 0; r < 4; ++r) {
                float q  = acc[0][m][n][r];
                float k0 = acc[1][m][n][r];
                float v0 = acc[2][m][n][r];
                float k1 = __shfl_xor(k0, 1);
                float k2 = __shfl_xor(k0, 2);
                float k3 = __shfl_xor(k0, 3);
                float v1 = __shfl_xor(v0, 1);
                float v2 = __shfl_xor(v0, 2);
                float v3 = __shfl_xor(v0, 3);
                float s0 = q * k0, s1 = q * k1, s2 = q * k2, s3 = q * k3;
                float mx = fmaxf(fmaxf(s0, s1), fmaxf(s2, s3));
                float e0 = __expf(s0 - mx), e1 = __expf(s1 - mx);
                float e2 = __expf(s2 - mx), e3 = __expf(s3 - mx);
                float num = e0 * v0 + e1 * v1 + e2 * v2 + e3 * v3;
                float den = e0 + e1 + e2 + e3;
                int row = bm + wm * 32 + m * 16 + fq * 4 + r;
                int oc  = bn + wn * 64 + n * 16 + fr;
                out[(size_t)row * F + oc] = num / den;
            }
        }
    }
}

extern "C" void kernel_launch(void* const* d_in, const int* in_sizes, int n_in,
                              void* d_out, int out_size, void* d_ws, size_t ws_size,
                              hipStream_t stream) {
    const float* x  = (const float*)d_in[0];
    const float* Wq = (const float*)d_in[1];
    const float* Wk = (const float*)d_in[2];
    const float* Wv = (const float*)d_in[3];
    float* out = (float*)d_out;

    unsigned short* xb  = (unsigned short*)d_ws;
    unsigned short* wqb = xb  + NE;
    unsigned short* wkb = wqb + NE;
    unsigned short* wvb = wkb + NE;
    unsigned short* qkv = wvb + NE;

    const int n4 = (int)(NE / 4);
    cvt_all<<<dim3(2048, 4), 256, 0, stream>>>(x, Wq, Wk, Wv, xb, wqb, wkb, wvb, n4);

    const size_t need_fast = NE * 2 * 7;      // ~235 MB
    if (ws_size >= need_fast) {
        gemm_qkv<<<1536, 256, 0, stream>>>(xb, wqb, wkb, wvb, qkv);
        attn_ep<<<4096, 256, 0, stream>>>(qkv, out);
    } else {
        dim3 grid(F / BN, F / BM);
        fused_qkv_attn<<<grid, NTHREADS, 0, stream>>>(xb, wqb, wkb, wvb, out);
    }
}